// Round 7
// baseline (24610.143 us; speedup 1.0000x reference)
//
#include <hip/hip_runtime.h>

// Problem constants
#define Bn 128
#define Tn 512
#define Vn 128
#define En 64
#define Ln 128
#define Hn 512
#define G4 2048
#define WGS 128
#define NTHR 512
#define NALL 65536
#define LSTR 520   // LDS row stride in u16
#define HL 260     // head1L row stride in f32

typedef unsigned short u16;
typedef unsigned int u32;
typedef __bf16 bf16x8 __attribute__((ext_vector_type(8)));
typedef float f32x4 __attribute__((ext_vector_type(4)));
typedef u32 u32x4 __attribute__((ext_vector_type(4)));

__device__ inline float bf2f(u16 h) {
    u32 u = ((u32)h) << 16;
    float f;
    __builtin_memcpy(&f, &u, 4);
    return f;
}
__device__ inline u16 f2bf(float f) {
    u32 u;
    __builtin_memcpy(&u, &f, 4);
    u32 r = (u + 0x7fffu + ((u >> 16) & 1u)) >> 16;
    return (u16)r;
}
__device__ inline u32 f2u(float f) { u32 u; __builtin_memcpy(&u, &f, 4); return u; }
__device__ inline float u2f(u32 u) { float f; __builtin_memcpy(&f, &u, 4); return f; }
__device__ inline float sigm(float x) { return 1.f / (1.f + expf(-x)); }
__device__ inline float leaky(float x) { return x > 0.f ? x : 0.2f * x; }
__device__ inline float softplus(float x) {
    return x > 0.f ? x + log1pf(expf(-x)) : log1pf(expf(x));
}

// ---- coherent (device-scope, LLC) vector memory ops; waitcnt INSIDE asm ----
__device__ inline void cload16(const u32* p, u32* w) {
    u32x4 v0, v1, v2, v3;
    asm volatile(
        "global_load_dwordx4 %0, %4, off sc0 sc1\n\t"
        "global_load_dwordx4 %1, %4, off offset:16 sc0 sc1\n\t"
        "global_load_dwordx4 %2, %4, off offset:32 sc0 sc1\n\t"
        "global_load_dwordx4 %3, %4, off offset:48 sc0 sc1\n\t"
        "s_waitcnt vmcnt(0)"
        : "=&v"(v0), "=&v"(v1), "=&v"(v2), "=&v"(v3)
        : "v"(p)
        : "memory");
    *(u32x4*)(w) = v0;
    *(u32x4*)(w + 4) = v1;
    *(u32x4*)(w + 8) = v2;
    *(u32x4*)(w + 12) = v3;
}
__device__ inline u32 cload1(const u32* p) {
    u32 v;
    asm volatile("global_load_dword %0, %1, off sc0 sc1\n\ts_waitcnt vmcnt(0)"
                 : "=v"(v) : "v"(p) : "memory");
    return v;
}
__device__ inline void cwait() { asm volatile("s_waitcnt vmcnt(0)" ::: "memory"); }
__device__ inline void cstore1(u32* p, u32 v) {
    asm volatile("global_store_dword %0, %1, off sc0 sc1" :: "v"(p), "v"(v) : "memory");
}

// Workspace layout (bytes)
#define OFF_FLAGS  0x000000   // grp flags: 16 u32 @ grp*16; heavy barrier: cnt@512 gen@528
#define OFF_B1SUM  0x002000
#define OFF_WP     0x004000
#define OFF_BIAS0  0x008000
#define OFF_CPAR   0x00A000   // f32: cg1,cbeta1,cg2,cbeta2; bo1@2048, bo2@2304, cb2@2560, cb1@3072, wo2f@3584
#define OFF_H0P    0x010000   // 128x512 u32 (hi|lo<<16)
#define OFF_H1P    0x050000
#define OFF_WO1TH  0x0B0000   // 256x512 bf16
#define OFF_WO1TL  0x0F0000
#define OFF_ZF     0x130000
#define OFF_CW1F   0x140000
#define OFF_CW2F   0x180000
#define OFF_CONDF  0x280000
#define OFF_YBUF   0x2C0000
#define OFF_BASE0  0x300000   // 1MB f32 (temp: wo1f in P0/P1)
#define OFF_EMBW   0x400000
#define OFF_W0HI   0x500000   // 2048x512 bf16 each
#define OFF_W0LO   0x700000
#define OFF_W1HI   0x900000
#define OFF_W1LO   0xB00000
#define OFF_WI1HI  0xD00000
#define OFF_WI1LO  0xF00000   // end 0x1100000

// heavy grid barrier (pre-phase only)
__device__ inline void gbar_heavy(int* cnt, int* gen) {
    __syncthreads();
    if (threadIdx.x == 0) {
        __threadfence();
        int g = __hip_atomic_load(gen, __ATOMIC_RELAXED, __HIP_MEMORY_SCOPE_AGENT);
        int arrived = __hip_atomic_fetch_add(cnt, 1, __ATOMIC_ACQ_REL, __HIP_MEMORY_SCOPE_AGENT);
        if (arrived == WGS - 1) {
            __hip_atomic_store(cnt, 0, __ATOMIC_RELAXED, __HIP_MEMORY_SCOPE_AGENT);
            __hip_atomic_store(gen, g + 1, __ATOMIC_RELEASE, __HIP_MEMORY_SCOPE_AGENT);
        } else {
            while (__hip_atomic_load(gen, __ATOMIC_ACQUIRE, __HIP_MEMORY_SCOPE_AGENT) == g)
                __builtin_amdgcn_s_sleep(1);
        }
        __threadfence();
    }
    __syncthreads();
}

// distributed flag poll: every lane loads one of the 16 group slots
__device__ inline void poll_group(const u32* gf, u32 sq) {
    const int l = threadIdx.x & 15;
    for (;;) {
        u32 v = cload1(gf + l);
        if (__all((int)(v >= sq))) break;
        __builtin_amdgcn_s_sleep(1);
    }
}

// unpack 16 packed u32 (hi|lo<<16) into bf16 hi/lo planes (16 u16 each)
__device__ inline void unpack16(const u32* w, u16* ph, u16* pl) {
    u32 hd[8], ld[8];
#pragma unroll
    for (int i = 0; i < 8; ++i) {
        hd[i] = (w[2 * i] & 0xFFFFu) | (w[2 * i + 1] << 16);
        ld[i] = (w[2 * i] >> 16) | (w[2 * i + 1] & 0xFFFF0000u);
    }
    *(u32x4*)(ph) = *(const u32x4*)(hd);
    *(u32x4*)(ph + 8) = *(const u32x4*)(hd + 4);
    *(u32x4*)(pl) = *(const u32x4*)(ld);
    *(u32x4*)(pl + 8) = *(const u32x4*)(ld + 4);
}

// dtype-safe staging (pre-phase)
__device__ inline void stage(float* dst, const void* src, int n, int gtid, bool isbf) {
    if (isbf) {
        const u16* s = (const u16*)src;
        for (int e = gtid; e < n; e += NALL) dst[e] = bf2f(s[e]);
    } else {
        const float* s = (const float*)src;
        for (int e = gtid; e < n; e += NALL) dst[e] = s[e];
    }
}
__device__ inline void stage_split(u16* hi, u16* lo, const void* src, int n, int gtid, bool isbf) {
    if (isbf) {
        const u16* s = (const u16*)src;
        for (int e = gtid; e < n; e += NALL) { hi[e] = s[e]; lo[e] = 0; }
    } else {
        const float* s = (const float*)src;
        for (int e = gtid; e < n; e += NALL) {
            float w = s[e];
            u16 h = f2bf(w);
            hi[e] = h;
            lo[e] = f2bf(w - bf2f(h));
        }
    }
}

template <bool ISBF>
__device__ inline float ldw(const void* p, size_t i) {
    if constexpr (ISBF) return bf2f(((const u16*)p)[i]);
    else return ((const float*)p)[i];
}

template <bool ISBF>
__device__ void phase5(const void* wih0, const void* emb, const float* __restrict__ condf,
                       const float* __restrict__ bias0f, float* __restrict__ base0,
                       float* __restrict__ embW, int gtid) {
    const int cc = gtid & 2047;
    const int bb0 = gtid >> 11;
    float b = bias0f[cc];
    float a0 = b, a1 = b, a2 = b, a3 = b;
    const float* c0p = condf + (size_t)bb0 * Hn;
    const float* c1p = condf + (size_t)(bb0 + 32) * Hn;
    const float* c2p = condf + (size_t)(bb0 + 64) * Hn;
    const float* c3p = condf + (size_t)(bb0 + 96) * Hn;
    const size_t wb = (size_t)cc * 578 + 64;
    for (int k = 0; k < Hn; ++k) {
        float w = ldw<ISBF>(wih0, wb + k);
        a0 += c0p[k] * w; a1 += c1p[k] * w; a2 += c2p[k] * w; a3 += c3p[k] * w;
    }
    base0[(size_t)bb0 * G4 + cc] = a0;
    base0[(size_t)(bb0 + 32) * G4 + cc] = a1;
    base0[(size_t)(bb0 + 64) * G4 + cc] = a2;
    base0[(size_t)(bb0 + 96) * G4 + cc] = a3;
    float e0 = 0.f, e1 = 0.f, e2 = 0.f, e3 = 0.f;
    const size_t wb2 = (size_t)cc * 578;
    for (int k = 0; k < En; ++k) {
        float w = ldw<ISBF>(wih0, wb2 + k);
        e0 += ldw<ISBF>(emb, (size_t)bb0 * En + k) * w;
        e1 += ldw<ISBF>(emb, (size_t)(bb0 + 32) * En + k) * w;
        e2 += ldw<ISBF>(emb, (size_t)(bb0 + 64) * En + k) * w;
        e3 += ldw<ISBF>(emb, (size_t)(bb0 + 96) * En + k) * w;
    }
    embW[(size_t)bb0 * G4 + cc] = e0;
    embW[(size_t)(bb0 + 32) * G4 + cc] = e1;
    embW[(size_t)(bb0 + 64) * G4 + cc] = e2;
    embW[(size_t)(bb0 + 96) * G4 + cc] = e3;
}

__device__ inline void ln_leaky_row(const float* __restrict__ x, const float* __restrict__ gamma,
                                    const float* __restrict__ beta, float* __restrict__ out,
                                    float* red) {
    int tid = threadIdx.x;
    float v = x[tid];
    float s = v, s2 = v * v;
    for (int off = 32; off; off >>= 1) {
        s += __shfl_down(s, off);
        s2 += __shfl_down(s2, off);
    }
    int wv = tid >> 6;
    if ((tid & 63) == 0) { red[wv * 2] = s; red[wv * 2 + 1] = s2; }
    __syncthreads();
    if (tid == 0) {
        float ts = 0.f, ts2 = 0.f;
        for (int i = 0; i < 8; ++i) { ts += red[i * 2]; ts2 += red[i * 2 + 1]; }
        float m = ts / 512.f;
        float var = ts2 / 512.f - m * m;
        red[16] = m;
        red[17] = rsqrtf(var + 1e-5f);
    }
    __syncthreads();
    float m = red[16], rs = red[17];
    out[tid] = leaky((v - m) * rs * gamma[tid] + beta[tid]);
    __syncthreads();
}

__global__ void init_flags_kernel(int* flags) { flags[threadIdx.x] = 0; }

__global__ __launch_bounds__(NTHR, 1) void gen_kernel(
    const int* __restrict__ char_ids, const void* z, const void* emb,
    const void* cw1, const void* cb1, const void* cg1, const void* cbeta1,
    const void* cw2, const void* cb2, const void* cg2, const void* cbeta2,
    const void* wih0, const void* whh0, const void* bih0, const void* bhh0,
    const void* wih1, const void* whh1, const void* bih1, const void* bhh1,
    const void* wo1, const void* bo1, const void* wo2, const void* bo2,
    const void* init_t, void* outp, char* __restrict__ ws) {
    __shared__ u16 lh0h[16 * LSTR];
    __shared__ u16 lh0l[16 * LSTR];
    __shared__ u16 lh1h[16 * LSTR];
    __shared__ u16 lh1l[16 * LSTR];
    __shared__ float head1L[16 * HL];
    __shared__ float smemx[2048];
    __shared__ float pvs[32];
    __shared__ float red[34];

    int* flags = (int*)(ws + OFF_FLAGS);
    float* b1sum = (float*)(ws + OFF_B1SUM);
    float* wpb = (float*)(ws + OFF_WP);
    float* bias0f = (float*)(ws + OFF_BIAS0);
    float* cpar = (float*)(ws + OFF_CPAR);
    u32* h0p = (u32*)(ws + OFF_H0P);
    u32* h1p = (u32*)(ws + OFF_H1P);
    u16* wo1Th = (u16*)(ws + OFF_WO1TH);
    u16* wo1Tl = (u16*)(ws + OFF_WO1TL);
    float* zf = (float*)(ws + OFF_ZF);
    float* cw1f = (float*)(ws + OFF_CW1F);
    float* cw2f = (float*)(ws + OFF_CW2F);
    float* condf = (float*)(ws + OFF_CONDF);
    float* ybuf = (float*)(ws + OFF_YBUF);
    float* base0 = (float*)(ws + OFF_BASE0);
    float* embW = (float*)(ws + OFF_EMBW);
    u16* W0hi = (u16*)(ws + OFF_W0HI);
    u16* W0lo = (u16*)(ws + OFF_W0LO);
    u16* W1hi = (u16*)(ws + OFF_W1HI);
    u16* W1lo = (u16*)(ws + OFF_W1LO);
    u16* Wi1hi = (u16*)(ws + OFF_WI1HI);
    u16* Wi1lo = (u16*)(ws + OFF_WI1LO);
    float* wo1f = base0;  // temp until P5

    const bool isbf = (((const u32*)cg1)[0] == 0x3F803F80u);

    const int g = blockIdx.x;
    const int tid = threadIdx.x;
    const int wv = tid >> 6;
    const int grp = g >> 4;     // 0..7: 16 batch rows each
    const int ut = g & 15;      // unit block: 32 units
    const int gw = wv & 3;      // gate
    const int ch = wv >> 2;     // col half
    const int R0g = grp * 16;
    const int colb = gw * 512 + ut * 32 + ch * 16;
    const int lane = tid & 63;
    const int n = lane & 15;
    const int q = lane >> 4;
    const int gtid = g * NTHR + tid;
    const f32x4 Z4 = {0.f, 0.f, 0.f, 0.f};

    u32* gf = (u32*)flags + grp * 16;   // 16 slots, one cacheline
    u32* gfl = gf + ut;                 // this WG's slot
    int* hcnt = flags + 512;
    int* hgen = flags + 528;

    // ---------------- P0: stage everything ----------------
    stage_split(W0hi, W0lo, whh0, G4 * Hn, gtid, isbf);
    stage_split(W1hi, W1lo, whh1, G4 * Hn, gtid, isbf);
    stage_split(Wi1hi, Wi1lo, wih1, G4 * Hn, gtid, isbf);
    stage(zf, z, Bn * Ln, gtid, isbf);
    stage(cw1f, cw1, Ln * Hn, gtid, isbf);
    stage(cw2f, cw2, Hn * Hn, gtid, isbf);
    stage(cpar + 0, cg1, 512, gtid, isbf);
    stage(cpar + 512, cbeta1, 512, gtid, isbf);
    stage(cpar + 1024, cg2, 512, gtid, isbf);
    stage(cpar + 1536, cbeta2, 512, gtid, isbf);
    stage(cpar + 2048, bo1, 256, gtid, isbf);
    stage(cpar + 2304, bo2, 2, gtid, isbf);
    stage(cpar + 2560, cb2, 512, gtid, isbf);
    stage(cpar + 3072, cb1, 512, gtid, isbf);
    stage(cpar + 3584, wo2, 256 * 2, gtid, isbf);
    stage(wo1f, wo1, Hn * 256, gtid, isbf);
    if (isbf) {
        if (gtid < G4) b1sum[gtid] = bf2f(((const u16*)bih1)[gtid]) + bf2f(((const u16*)bhh1)[gtid]);
        if (gtid < G4) bias0f[gtid] = bf2f(((const u16*)bih0)[gtid]) + bf2f(((const u16*)bhh0)[gtid]);
        if (gtid < 4096) {
            size_t ix = (size_t)(gtid >> 1) * 578 + 576 + (gtid & 1);
            wpb[gtid] = bf2f(((const u16*)wih0)[ix]);
        }
    } else {
        if (gtid < G4) b1sum[gtid] = ((const float*)bih1)[gtid] + ((const float*)bhh1)[gtid];
        if (gtid < G4) bias0f[gtid] = ((const float*)bih0)[gtid] + ((const float*)bhh0)[gtid];
        if (gtid < 4096) {
            size_t ix = (size_t)(gtid >> 1) * 578 + 576 + (gtid & 1);
            wpb[gtid] = ((const float*)wih0)[ix];
        }
    }
    gbar_heavy(hcnt, hgen);
    // ---------------- P1 ----------------
    {
        int bb = gtid >> 9, nn = gtid & 511;
        float a = cpar[3072 + nn];
        const float* zr = zf + bb * Ln;
        for (int k = 0; k < Ln; ++k) a += zr[k] * cw1f[k * Hn + nn];
        ybuf[gtid] = a;
    }
    for (int e = gtid; e < 256 * Hn; e += NALL) {
        int nn = e >> 9, kk = e & 511;
        float w = wo1f[kk * 256 + nn];
        u16 hv = f2bf(w);
        wo1Th[e] = hv;
        wo1Tl[e] = f2bf(w - bf2f(hv));
    }
    gbar_heavy(hcnt, hgen);
    ln_leaky_row(ybuf + g * Hn, cpar + 0, cpar + 512, condf + g * Hn, red);
    gbar_heavy(hcnt, hgen);
    {
        float a = cpar[2560 + tid];
        const float* crow = condf + g * Hn;
        for (int k = 0; k < Hn; ++k) a += crow[k] * cw2f[k * Hn + tid];
        ybuf[g * Hn + tid] = a;
    }
    gbar_heavy(hcnt, hgen);
    ln_leaky_row(ybuf + g * Hn, cpar + 1024, cpar + 1536, condf + g * Hn, red);
    gbar_heavy(hcnt, hgen);
    if (isbf) phase5<true>(wih0, emb, condf, bias0f, base0, embW, gtid);
    else phase5<false>(wih0, emb, condf, bias0f, base0, embW, gtid);
    gbar_heavy(hcnt, hgen);  // invalidates L2: cached reads below see fresh data

    // ---------------- main loop ----------------
    float c0 = 0.f, c1 = 0.f;
    const int bb = R0g + (tid >> 5);
    const int uu = ut * 32 + (tid & 31);
    const float* bo1f = cpar + 2048;
    const float* bo2f = cpar + 2304;
    const float* wo2f = cpar + 3584;
    const int srow = tid >> 5;         // staging row 0..15
    const int kof = (tid & 31) * 16;   // staging offset (elements)

    // init LDS h planes = 0 (h(-1) = 0); pvs = init_timing
    for (int e = tid; e < 16 * LSTR; e += NTHR) {
        lh0h[e] = 0; lh0l[e] = 0; lh1h[e] = 0; lh1l[e] = 0;
    }
    if (tid < 32) pvs[tid] = isbf ? bf2f(((const u16*)init_t)[tid & 1])
                                  : ((const float*)init_t)[tid & 1];

    for (int t = 0; t < Tn; ++t) {
        __syncthreads();
        // ---- A: load h1(t-1); GEMMs whh0·h0 + whh1·h1 + head; gates0 -> h0(t) ----
        if (t >= 1) {
            poll_group(gf, 2 * (u32)t);
            u32 w[16];
            cload16(h1p + (size_t)(R0g + srow) * Hn + kof, w);
            unpack16(w, lh1h + srow * LSTR + kof, lh1l + srow * LSTR + kof);
        }
        __syncthreads();
        f32x4 x0a = Z4, x0b = Z4, x0c = Z4, x1a = Z4, x1b = Z4, x1c = Z4;
        {
            const int arow = n * LSTR;
            const u16* B0h = W0hi + (size_t)(colb + n) * Hn;
            const u16* B0l = W0lo + (size_t)(colb + n) * Hn;
            const u16* B1h = W1hi + (size_t)(colb + n) * Hn;
            const u16* B1l = W1lo + (size_t)(colb + n) * Hn;
#pragma unroll 4
            for (int it = 0; it < 16; ++it) {
                const int ko = it * 32 + q * 8;
                bf16x8 a0h = *(const bf16x8*)(lh0h + arow + ko);
                bf16x8 a0l = *(const bf16x8*)(lh0l + arow + ko);
                bf16x8 a1h = *(const bf16x8*)(lh1h + arow + ko);
                bf16x8 a1l = *(const bf16x8*)(lh1l + arow + ko);
                bf16x8 b0h = *(const bf16x8*)(B0h + ko);
                bf16x8 b0l = *(const bf16x8*)(B0l + ko);
                bf16x8 b1h = *(const bf16x8*)(B1h + ko);
                bf16x8 b1l = *(const bf16x8*)(B1l + ko);
                x0a = __builtin_amdgcn_mfma_f32_16x16x32_bf16(a0h, b0h, x0a, 0, 0, 0);
                x0b = __builtin_amdgcn_mfma_f32_16x16x32_bf16(a0l, b0h, x0b, 0, 0, 0);
                x0c = __builtin_amdgcn_mfma_f32_16x16x32_bf16(a0h, b0l, x0c, 0, 0, 0);
                x1a = __builtin_amdgcn_mfma_f32_16x16x32_bf16(a1h, b1h, x1a, 0, 0, 0);
                x1b = __builtin_amdgcn_mfma_f32_16x16x32_bf16(a1l, b1h, x1b, 0, 0, 0);
                x1c = __builtin_amdgcn_mfma_f32_16x16x32_bf16(a1h, b1l, x1c, 0, 0, 0);
            }
        }
        f32x4 acc0 = x0a + x0b + x0c;
        f32x4 acc1 = x1a + x1b + x1c;
        // head1 (redundant per WG): wave wv covers head cols [wv*32, wv*32+32)
        if (t >= 1) {
#pragma unroll
            for (int tile = 0; tile < 2; ++tile) {
                const int c0h = wv * 32 + tile * 16;
                f32x4 ha = Z4, hb = Z4, hc = Z4;
                const u16* Bh = wo1Th + (size_t)(c0h + n) * Hn;
                const u16* Bl = wo1Tl + (size_t)(c0h + n) * Hn;
                const int arow = n * LSTR;
#pragma unroll 4
                for (int it = 0; it < 16; ++it) {
                    const int ko = it * 32 + q * 8;
                    bf16x8 ah = *(const bf16x8*)(lh1h + arow + ko);
                    bf16x8 al = *(const bf16x8*)(lh1l + arow + ko);
                    bf16x8 vh = *(const bf16x8*)(Bh + ko);
                    bf16x8 vl = *(const bf16x8*)(Bl + ko);
                    ha = __builtin_amdgcn_mfma_f32_16x16x32_bf16(ah, vh, ha, 0, 0, 0);
                    hb = __builtin_amdgcn_mfma_f32_16x16x32_bf16(al, vh, hb, 0, 0, 0);
                    hc = __builtin_amdgcn_mfma_f32_16x16x32_bf16(ah, vl, hc, 0, 0, 0);
                }
                f32x4 hh = ha + hb + hc;
#pragma unroll
                for (int r = 0; r < 4; ++r) {
                    int cc = c0h + n;
                    head1L[(q * 4 + r) * HL + cc] = leaky(hh[r] + bo1f[cc]);
                }
            }
        }
#pragma unroll
        for (int r = 0; r < 4; ++r)
            smemx[gw * 512 + (q * 4 + r) * 32 + ch * 16 + n] = acc0[r];
        __syncthreads();
        // head2 (local): 32 (row,j) groups of 16 threads
        if (t >= 1) {
            const int pr = tid >> 4;
            const int rowl = pr >> 1, jo = pr & 1;
            const int ks = (tid & 15) * 16;
            float s = 0.f;
#pragma unroll
            for (int i = 0; i < 16; ++i) s += head1L[rowl * HL + ks + i] * wo2f[(ks + i) * 2 + jo];
            s += __shfl_xor(s, 1, 16);
            s += __shfl_xor(s, 2, 16);
            s += __shfl_xor(s, 4, 16);
            s += __shfl_xor(s, 8, 16);
            if ((tid & 15) == 0) {
                float y = softplus(s + bo2f[jo]) + 0.005f;
                pvs[pr] = y;
                if (ut == 0) {
                    size_t oi = ((size_t)(R0g + rowl) * Tn + (t - 1)) * 2 + jo;
                    if (isbf) ((u16*)outp)[oi] = f2bf(y);
                    else ((float*)outp)[oi] = y;
                }
            }
        }
        __syncthreads();
        {
            int id = char_ids[bb * Tn + t];
            float pv0 = pvs[(tid >> 5) * 2], pv1 = pvs[(tid >> 5) * 2 + 1];
            float gv[4];
#pragma unroll
            for (int gi = 0; gi < 4; ++gi) {
                int cc = gi * 512 + uu;
                gv[gi] = smemx[gi * 512 + (tid >> 5) * 32 + (tid & 31)] +
                         base0[(size_t)bb * G4 + cc] + embW[(size_t)id * G4 + cc] +
                         pv0 * wpb[2 * cc] + pv1 * wpb[2 * cc + 1];
            }
            float ig = sigm(gv[0]), fg = sigm(gv[1]), gg = tanhf(gv[2]), og = sigm(gv[3]);
            c0 = fg * c0 + ig * gg;
            float h = og * tanhf(c0);
            u16 hv = f2bf(h);
            u16 lv = f2bf(h - bf2f(hv));
            cstore1(h0p + (size_t)bb * Hn + uu, (u32)hv | ((u32)lv << 16));
        }
        cwait();
        __syncthreads();
        if (tid == 0) cstore1(gfl, 2 * (u32)t + 1);

        // ---- B: exchange h0(t); GEMM wih1·h0(t); gates1 -> h1(t) ----
        poll_group(gf, 2 * (u32)t + 1);
        {
            u32 w[16];
            cload16(h0p + (size_t)(R0g + srow) * Hn + kof, w);
            unpack16(w, lh0h + srow * LSTR + kof, lh0l + srow * LSTR + kof);
        }
        __syncthreads();
        {
            const int arow = n * LSTR;
            const u16* Bh = Wi1hi + (size_t)(colb + n) * Hn;
            const u16* Bl = Wi1lo + (size_t)(colb + n) * Hn;
            f32x4 za = Z4, zb = Z4, zc = Z4;
#pragma unroll 4
            for (int it = 0; it < 16; ++it) {
                const int ko = it * 32 + q * 8;
                bf16x8 ah = *(const bf16x8*)(lh0h + arow + ko);
                bf16x8 al = *(const bf16x8*)(lh0l + arow + ko);
                bf16x8 bh = *(const bf16x8*)(Bh + ko);
                bf16x8 bl = *(const bf16x8*)(Bl + ko);
                za = __builtin_amdgcn_mfma_f32_16x16x32_bf16(ah, bh, za, 0, 0, 0);
                zb = __builtin_amdgcn_mfma_f32_16x16x32_bf16(al, bh, zb, 0, 0, 0);
                zc = __builtin_amdgcn_mfma_f32_16x16x32_bf16(ah, bl, zc, 0, 0, 0);
            }
            acc1 = acc1 + za + zb + zc;
        }
#pragma unroll
        for (int r = 0; r < 4; ++r)
            smemx[gw * 512 + (q * 4 + r) * 32 + ch * 16 + n] = acc1[r];
        __syncthreads();
        {
            float gv[4];
#pragma unroll
            for (int gi = 0; gi < 4; ++gi) {
                int cc = gi * 512 + uu;
                gv[gi] = smemx[gi * 512 + (tid >> 5) * 32 + (tid & 31)] + b1sum[cc];
            }
            float ig = sigm(gv[0]), fg = sigm(gv[1]), gg = tanhf(gv[2]), og = sigm(gv[3]);
            c1 = fg * c1 + ig * gg;
            float h = og * tanhf(c1);
            u16 hv = f2bf(h);
            u16 lv = f2bf(h - bf2f(hv));
            cstore1(h1p + (size_t)bb * Hn + uu, (u32)hv | ((u32)lv << 16));
        }
        cwait();
        __syncthreads();
        if (tid == 0) cstore1(gfl, 2 * (u32)t + 2);
    }

    // ---------------- epilogue: head for t = 511 ----------------
    __syncthreads();
    poll_group(gf, 2 * (u32)Tn);
    {
        u32 w[16];
        cload16(h1p + (size_t)(R0g + srow) * Hn + kof, w);
        unpack16(w, lh1h + srow * LSTR + kof, lh1l + srow * LSTR + kof);
    }
    __syncthreads();
    {
#pragma unroll
        for (int tile = 0; tile < 2; ++tile) {
            const int c0h = wv * 32 + tile * 16;
            f32x4 ha = Z4, hb = Z4, hc = Z4;
            const u16* Bh = wo1Th + (size_t)(c0h + n) * Hn;
            const u16* Bl = wo1Tl + (size_t)(c0h + n) * Hn;
            const int arow = n * LSTR;
#pragma unroll 4
            for (int it = 0; it < 16; ++it) {
                const int ko = it * 32 + q * 8;
                bf16x8 ah = *(const bf16x8*)(lh1h + arow + ko);
                bf16x8 al = *(const bf16x8*)(lh1l + arow + ko);
                bf16x8 vh = *(const bf16x8*)(Bh + ko);
                bf16x8 vl = *(const bf16x8*)(Bl + ko);
                ha = __builtin_amdgcn_mfma_f32_16x16x32_bf16(ah, vh, ha, 0, 0, 0);
                hb = __builtin_amdgcn_mfma_f32_16x16x32_bf16(al, vh, hb, 0, 0, 0);
                hc = __builtin_amdgcn_mfma_f32_16x16x32_bf16(ah, vl, hc, 0, 0, 0);
            }
            f32x4 hh = ha + hb + hc;
#pragma unroll
            for (int r = 0; r < 4; ++r) {
                int cc = c0h + n;
                head1L[(q * 4 + r) * HL + cc] = leaky(hh[r] + bo1f[cc]);
            }
        }
    }
    __syncthreads();
    if (ut == 0) {
        const int pr = tid >> 4;
        const int rowl = pr >> 1, jo = pr & 1;
        const int ks = (tid & 15) * 16;
        float s = 0.f;
#pragma unroll
        for (int i = 0; i < 16; ++i) s += head1L[rowl * HL + ks + i] * wo2f[(ks + i) * 2 + jo];
        s += __shfl_xor(s, 1, 16);
        s += __shfl_xor(s, 2, 16);
        s += __shfl_xor(s, 4, 16);
        s += __shfl_xor(s, 8, 16);
        if ((tid & 15) == 0) {
            float y = softplus(s + bo2f[jo]) + 0.005f;
            size_t oi = ((size_t)(R0g + rowl) * Tn + (Tn - 1)) * 2 + jo;
            if (isbf) ((u16*)outp)[oi] = f2bf(y);
            else ((float*)outp)[oi] = y;
        }
    }
}

extern "C" void kernel_launch(void* const* d_in, const int* in_sizes, int n_in,
                              void* d_out, int out_size, void* d_ws, size_t ws_size,
                              hipStream_t stream) {
    (void)in_sizes; (void)n_in; (void)out_size; (void)ws_size;
    init_flags_kernel<<<1, 1024, 0, stream>>>((int*)d_ws);
    gen_kernel<<<WGS, NTHR, 0, stream>>>(
        (const int*)d_in[0], d_in[1], d_in[2], d_in[3], d_in[4], d_in[5], d_in[6], d_in[7],
        d_in[8], d_in[9], d_in[10], d_in[11], d_in[12], d_in[13], d_in[14], d_in[15], d_in[16],
        d_in[17], d_in[18], d_in[19], d_in[20], d_in[21], d_in[22], d_in[23],
        d_out, (char*)d_ws);
}

// Round 8
// 14923.399 us; speedup vs baseline: 1.6491x; 1.6491x over previous
//
#include <hip/hip_runtime.h>

// Problem constants
#define Bn 128
#define Tn 512
#define Vn 128
#define En 64
#define Ln 128
#define Hn 512
#define G4 2048
#define WGS 128
#define NTHR 512
#define NALL 65536
#define LSTR 520   // LDS row stride in u16 (16B-aligned rows)
#define GRPS 4
#define WPG 32     // WGs per group
#define RPG 32     // batch rows per group

typedef unsigned short u16;
typedef unsigned int u32;
typedef __bf16 bf16x8 __attribute__((ext_vector_type(8)));
typedef float f32x4 __attribute__((ext_vector_type(4)));
typedef u32 u32x4 __attribute__((ext_vector_type(4)));

__device__ inline float bf2f(u16 h) {
    u32 u = ((u32)h) << 16;
    float f;
    __builtin_memcpy(&f, &u, 4);
    return f;
}
__device__ inline u16 f2bf(float f) {
    u32 u;
    __builtin_memcpy(&u, &f, 4);
    u32 r = (u + 0x7fffu + ((u >> 16) & 1u)) >> 16;
    return (u16)r;
}
__device__ inline u32 f2u(float f) { u32 u; __builtin_memcpy(&u, &f, 4); return u; }
__device__ inline float u2f(u32 u) { float f; __builtin_memcpy(&f, &u, 4); return f; }
__device__ inline float sigm(float x) { return 1.f / (1.f + expf(-x)); }
__device__ inline float leaky(float x) { return x > 0.f ? x : 0.2f * x; }
__device__ inline float softplus(float x) {
    return x > 0.f ? x + log1pf(expf(-x)) : log1pf(expf(x));
}

// ---- coherent (device-scope) vector ops; waitcnt INSIDE asm (round-5 lesson) ----
__device__ inline void cload16(const u32* p, u32* w) {
    u32x4 v0, v1, v2, v3;
    asm volatile(
        "global_load_dwordx4 %0, %4, off sc0 sc1\n\t"
        "global_load_dwordx4 %1, %4, off offset:16 sc0 sc1\n\t"
        "global_load_dwordx4 %2, %4, off offset:32 sc0 sc1\n\t"
        "global_load_dwordx4 %3, %4, off offset:48 sc0 sc1\n\t"
        "s_waitcnt vmcnt(0)"
        : "=&v"(v0), "=&v"(v1), "=&v"(v2), "=&v"(v3)
        : "v"(p)
        : "memory");
    *(u32x4*)(w) = v0;
    *(u32x4*)(w + 4) = v1;
    *(u32x4*)(w + 8) = v2;
    *(u32x4*)(w + 12) = v3;
}
__device__ inline u32 cload1(const u32* p) {
    u32 v;
    asm volatile("global_load_dword %0, %1, off sc0 sc1\n\ts_waitcnt vmcnt(0)"
                 : "=v"(v) : "v"(p) : "memory");
    return v;
}
__device__ inline void cwait() { asm volatile("s_waitcnt vmcnt(0)" ::: "memory"); }
__device__ inline void cstore1(u32* p, u32 v) {
    asm volatile("global_store_dword %0, %1, off sc0 sc1" :: "v"(p), "v"(v) : "memory");
}

// Workspace layout (bytes)
#define OFF_FLAGS  0x000000   // grp: 32 slots @ grp*64, head-flag 16 slots @ grp*64+32; heavy cnt@512 gen@528
#define OFF_B1SUM  0x002000
#define OFF_WP     0x004000
#define OFF_BIAS0  0x008000
#define OFF_CPAR   0x00A000   // f32: cg1,cbeta1,cg2,cbeta2; bo1@2048, bo2@2304, cb2@2560, cb1@3072, wo2f@3584
#define OFF_H0P    0x010000   // 128x512 u32 (hi|lo<<16)
#define OFF_H1P    0x050000
#define OFF_PART   0x090000   // partials: grp*1024 f32: [row][j][hw16]
#define OFF_WO1TH  0x0B0000   // 256x512 bf16
#define OFF_WO1TL  0x0F0000
#define OFF_ZF     0x130000
#define OFF_CW1F   0x140000
#define OFF_CW2F   0x180000
#define OFF_CONDF  0x280000
#define OFF_YBUF   0x2C0000
#define OFF_BASE0  0x300000   // 1MB f32 (temp: wo1f in P0/P1)
#define OFF_EMBW   0x400000
#define OFF_W0HI   0x500000   // 2048x512 bf16 each
#define OFF_W0LO   0x700000
#define OFF_W1HI   0x900000
#define OFF_W1LO   0xB00000
#define OFF_WI1HI  0xD00000
#define OFF_WI1LO  0xF00000   // end 0x1100000

// heavy grid barrier (pre-phase only)
__device__ inline void gbar_heavy(int* cnt, int* gen) {
    __syncthreads();
    if (threadIdx.x == 0) {
        __threadfence();
        int g = __hip_atomic_load(gen, __ATOMIC_RELAXED, __HIP_MEMORY_SCOPE_AGENT);
        int arrived = __hip_atomic_fetch_add(cnt, 1, __ATOMIC_ACQ_REL, __HIP_MEMORY_SCOPE_AGENT);
        if (arrived == WGS - 1) {
            __hip_atomic_store(cnt, 0, __ATOMIC_RELAXED, __HIP_MEMORY_SCOPE_AGENT);
            __hip_atomic_store(gen, g + 1, __ATOMIC_RELEASE, __HIP_MEMORY_SCOPE_AGENT);
        } else {
            while (__hip_atomic_load(gen, __ATOMIC_ACQUIRE, __HIP_MEMORY_SCOPE_AGENT) == g)
                __builtin_amdgcn_s_sleep(1);
        }
        __threadfence();
    }
    __syncthreads();
}

__device__ inline void poll32(const u32* gf, u32 sq) {
    const int l = threadIdx.x & 31;
    for (;;) {
        u32 v = cload1(gf + l);
        if (__all((int)(v >= sq))) break;
        __builtin_amdgcn_s_sleep(4);
    }
}
__device__ inline void poll16(const u32* gf, u32 sq) {
    const int l = threadIdx.x & 15;
    for (;;) {
        u32 v = cload1(gf + l);
        if (__all((int)(v >= sq))) break;
        __builtin_amdgcn_s_sleep(4);
    }
}

// unpack 16 packed u32 (hi|lo<<16) into bf16 hi/lo planes
__device__ inline void unpack16(const u32* w, u16* ph, u16* pl) {
    u32 hd[8], ld[8];
#pragma unroll
    for (int i = 0; i < 8; ++i) {
        hd[i] = (w[2 * i] & 0xFFFFu) | (w[2 * i + 1] << 16);
        ld[i] = (w[2 * i] >> 16) | (w[2 * i + 1] & 0xFFFF0000u);
    }
    *(u32x4*)(ph) = *(const u32x4*)(hd);
    *(u32x4*)(ph + 8) = *(const u32x4*)(hd + 4);
    *(u32x4*)(pl) = *(const u32x4*)(ld);
    *(u32x4*)(pl + 8) = *(const u32x4*)(ld + 4);
}

// M=32/N=16 tile via 2 stacked 16x16 MFMAs sharing B-frags, 3 hi/lo chains, K=512
#define MF(a, b, c) __builtin_amdgcn_mfma_f32_16x16x32_bf16(a, b, c, 0, 0, 0)
__device__ inline void gemm32_3(const u16* __restrict__ Ah, const u16* __restrict__ Al,
                                const u16* __restrict__ Bhb, const u16* __restrict__ Blb,
                                int colb, int n, int q, f32x4 acc[2][3]) {
    const u16* Bh = Bhb + (size_t)(colb + n) * Hn;
    const u16* Bl = Blb + (size_t)(colb + n) * Hn;
    const int a0 = n * LSTR;
    const int a1 = (16 + n) * LSTR;
#pragma unroll 4
    for (int it = 0; it < 16; ++it) {
        const int ko = it * 32 + q * 8;
        bf16x8 bh = *(const bf16x8*)(Bh + ko);
        bf16x8 bl = *(const bf16x8*)(Bl + ko);
        bf16x8 ah0 = *(const bf16x8*)(Ah + a0 + ko);
        bf16x8 al0 = *(const bf16x8*)(Al + a0 + ko);
        bf16x8 ah1 = *(const bf16x8*)(Ah + a1 + ko);
        bf16x8 al1 = *(const bf16x8*)(Al + a1 + ko);
        acc[0][0] = MF(ah0, bh, acc[0][0]);
        acc[0][1] = MF(al0, bh, acc[0][1]);
        acc[0][2] = MF(ah0, bl, acc[0][2]);
        acc[1][0] = MF(ah1, bh, acc[1][0]);
        acc[1][1] = MF(al1, bh, acc[1][1]);
        acc[1][2] = MF(ah1, bl, acc[1][2]);
    }
}

// dtype-safe staging (pre-phase)
__device__ inline void stage(float* dst, const void* src, int n, int gtid, bool isbf) {
    if (isbf) {
        const u16* s = (const u16*)src;
        for (int e = gtid; e < n; e += NALL) dst[e] = bf2f(s[e]);
    } else {
        const float* s = (const float*)src;
        for (int e = gtid; e < n; e += NALL) dst[e] = s[e];
    }
}
__device__ inline void stage_split(u16* hi, u16* lo, const void* src, int n, int gtid, bool isbf) {
    if (isbf) {
        const u16* s = (const u16*)src;
        for (int e = gtid; e < n; e += NALL) { hi[e] = s[e]; lo[e] = 0; }
    } else {
        const float* s = (const float*)src;
        for (int e = gtid; e < n; e += NALL) {
            float w = s[e];
            u16 h = f2bf(w);
            hi[e] = h;
            lo[e] = f2bf(w - bf2f(h));
        }
    }
}

template <bool ISBF>
__device__ inline float ldw(const void* p, size_t i) {
    if constexpr (ISBF) return bf2f(((const u16*)p)[i]);
    else return ((const float*)p)[i];
}

template <bool ISBF>
__device__ void phase5(const void* wih0, const void* emb, const float* __restrict__ condf,
                       const float* __restrict__ bias0f, float* __restrict__ base0,
                       float* __restrict__ embW, int gtid) {
    const int cc = gtid & 2047;
    const int bb0 = gtid >> 11;
    float b = bias0f[cc];
    float a0 = b, a1 = b, a2 = b, a3 = b;
    const float* c0p = condf + (size_t)bb0 * Hn;
    const float* c1p = condf + (size_t)(bb0 + 32) * Hn;
    const float* c2p = condf + (size_t)(bb0 + 64) * Hn;
    const float* c3p = condf + (size_t)(bb0 + 96) * Hn;
    const size_t wb = (size_t)cc * 578 + 64;
    for (int k = 0; k < Hn; ++k) {
        float w = ldw<ISBF>(wih0, wb + k);
        a0 += c0p[k] * w; a1 += c1p[k] * w; a2 += c2p[k] * w; a3 += c3p[k] * w;
    }
    base0[(size_t)bb0 * G4 + cc] = a0;
    base0[(size_t)(bb0 + 32) * G4 + cc] = a1;
    base0[(size_t)(bb0 + 64) * G4 + cc] = a2;
    base0[(size_t)(bb0 + 96) * G4 + cc] = a3;
    float e0 = 0.f, e1 = 0.f, e2 = 0.f, e3 = 0.f;
    const size_t wb2 = (size_t)cc * 578;
    for (int k = 0; k < En; ++k) {
        float w = ldw<ISBF>(wih0, wb2 + k);
        e0 += ldw<ISBF>(emb, (size_t)bb0 * En + k) * w;
        e1 += ldw<ISBF>(emb, (size_t)(bb0 + 32) * En + k) * w;
        e2 += ldw<ISBF>(emb, (size_t)(bb0 + 64) * En + k) * w;
        e3 += ldw<ISBF>(emb, (size_t)(bb0 + 96) * En + k) * w;
    }
    embW[(size_t)bb0 * G4 + cc] = e0;
    embW[(size_t)(bb0 + 32) * G4 + cc] = e1;
    embW[(size_t)(bb0 + 64) * G4 + cc] = e2;
    embW[(size_t)(bb0 + 96) * G4 + cc] = e3;
}

__device__ inline void ln_leaky_row(const float* __restrict__ x, const float* __restrict__ gamma,
                                    const float* __restrict__ beta, float* __restrict__ out,
                                    float* red) {
    int tid = threadIdx.x;
    float v = x[tid];
    float s = v, s2 = v * v;
    for (int off = 32; off; off >>= 1) {
        s += __shfl_down(s, off);
        s2 += __shfl_down(s2, off);
    }
    int wv = tid >> 6;
    if ((tid & 63) == 0) { red[wv * 2] = s; red[wv * 2 + 1] = s2; }
    __syncthreads();
    if (tid == 0) {
        float ts = 0.f, ts2 = 0.f;
        for (int i = 0; i < 8; ++i) { ts += red[i * 2]; ts2 += red[i * 2 + 1]; }
        float m = ts / 512.f;
        float var = ts2 / 512.f - m * m;
        red[16] = m;
        red[17] = rsqrtf(var + 1e-5f);
    }
    __syncthreads();
    float m = red[16], rs = red[17];
    out[tid] = leaky((v - m) * rs * gamma[tid] + beta[tid]);
    __syncthreads();
}

__global__ void init_flags_kernel(int* flags) { flags[threadIdx.x] = 0; }

__global__ __launch_bounds__(NTHR, 1) void gen_kernel(
    const int* __restrict__ char_ids, const void* z, const void* emb,
    const void* cw1, const void* cb1, const void* cg1, const void* cbeta1,
    const void* cw2, const void* cb2, const void* cg2, const void* cbeta2,
    const void* wih0, const void* whh0, const void* bih0, const void* bhh0,
    const void* wih1, const void* whh1, const void* bih1, const void* bhh1,
    const void* wo1, const void* bo1, const void* wo2, const void* bo2,
    const void* init_t, void* outp, char* __restrict__ ws) {
    __shared__ u16 lh0h[RPG * LSTR];
    __shared__ u16 lh0l[RPG * LSTR];
    __shared__ u16 lh1h[RPG * LSTR];
    __shared__ u16 lh1l[RPG * LSTR];
    __shared__ float smemx[2048];
    __shared__ float pvs[64];
    __shared__ float red[34];

    int* flags = (int*)(ws + OFF_FLAGS);
    float* b1sum = (float*)(ws + OFF_B1SUM);
    float* wpb = (float*)(ws + OFF_WP);
    float* bias0f = (float*)(ws + OFF_BIAS0);
    float* cpar = (float*)(ws + OFF_CPAR);
    u32* h0p = (u32*)(ws + OFF_H0P);
    u32* h1p = (u32*)(ws + OFF_H1P);
    float* partf = (float*)(ws + OFF_PART);
    u16* wo1Th = (u16*)(ws + OFF_WO1TH);
    u16* wo1Tl = (u16*)(ws + OFF_WO1TL);
    float* zf = (float*)(ws + OFF_ZF);
    float* cw1f = (float*)(ws + OFF_CW1F);
    float* cw2f = (float*)(ws + OFF_CW2F);
    float* condf = (float*)(ws + OFF_CONDF);
    float* ybuf = (float*)(ws + OFF_YBUF);
    float* base0 = (float*)(ws + OFF_BASE0);
    float* embW = (float*)(ws + OFF_EMBW);
    u16* W0hi = (u16*)(ws + OFF_W0HI);
    u16* W0lo = (u16*)(ws + OFF_W0LO);
    u16* W1hi = (u16*)(ws + OFF_W1HI);
    u16* W1lo = (u16*)(ws + OFF_W1LO);
    u16* Wi1hi = (u16*)(ws + OFF_WI1HI);
    u16* Wi1lo = (u16*)(ws + OFF_WI1LO);
    float* wo1f = base0;  // temp until P5

    const bool isbf = (((const u32*)cg1)[0] == 0x3F803F80u);

    const int g = blockIdx.x;
    const int tid = threadIdx.x;
    const int wv = tid >> 6;
    const int grp = g >> 5;     // 0..3: 32 batch rows each
    const int ut = g & 31;      // unit block: 16 units
    const int mat = wv >> 2;    // 0: whh0-side, 1: whh1/wih1-side
    const int gw = wv & 3;      // gate
    const int R0g = grp * RPG;
    const int colb = gw * 512 + ut * 16;
    const int lane = tid & 63;
    const int n = lane & 15;
    const int q = lane >> 4;
    const int gtid = g * NTHR + tid;
    const f32x4 Z4 = {0.f, 0.f, 0.f, 0.f};

    u32* gf = (u32*)flags + grp * 64;       // 32 step slots
    u32* gf2 = (u32*)flags + grp * 64 + 32; // 16 head slots
    u32* gfl = gf + ut;
    int* hcnt = flags + 512;
    int* hgen = flags + 528;
    float* part = partf + grp * 1024;       // [row][j][hw16]

    // ---------------- P0: stage everything ----------------
    stage_split(W0hi, W0lo, whh0, G4 * Hn, gtid, isbf);
    stage_split(W1hi, W1lo, whh1, G4 * Hn, gtid, isbf);
    stage_split(Wi1hi, Wi1lo, wih1, G4 * Hn, gtid, isbf);
    stage(zf, z, Bn * Ln, gtid, isbf);
    stage(cw1f, cw1, Ln * Hn, gtid, isbf);
    stage(cw2f, cw2, Hn * Hn, gtid, isbf);
    stage(cpar + 0, cg1, 512, gtid, isbf);
    stage(cpar + 512, cbeta1, 512, gtid, isbf);
    stage(cpar + 1024, cg2, 512, gtid, isbf);
    stage(cpar + 1536, cbeta2, 512, gtid, isbf);
    stage(cpar + 2048, bo1, 256, gtid, isbf);
    stage(cpar + 2304, bo2, 2, gtid, isbf);
    stage(cpar + 2560, cb2, 512, gtid, isbf);
    stage(cpar + 3072, cb1, 512, gtid, isbf);
    stage(cpar + 3584, wo2, 256 * 2, gtid, isbf);
    stage(wo1f, wo1, Hn * 256, gtid, isbf);
    if (gtid < NALL) { cstore1(h0p + gtid, 0); cstore1(h1p + gtid, 0); }
    if (isbf) {
        if (gtid < G4) b1sum[gtid] = bf2f(((const u16*)bih1)[gtid]) + bf2f(((const u16*)bhh1)[gtid]);
        if (gtid < G4) bias0f[gtid] = bf2f(((const u16*)bih0)[gtid]) + bf2f(((const u16*)bhh0)[gtid]);
        if (gtid < 4096) {
            size_t ix = (size_t)(gtid >> 1) * 578 + 576 + (gtid & 1);
            wpb[gtid] = bf2f(((const u16*)wih0)[ix]);
        }
    } else {
        if (gtid < G4) b1sum[gtid] = ((const float*)bih1)[gtid] + ((const float*)bhh1)[gtid];
        if (gtid < G4) bias0f[gtid] = ((const float*)bih0)[gtid] + ((const float*)bhh0)[gtid];
        if (gtid < 4096) {
            size_t ix = (size_t)(gtid >> 1) * 578 + 576 + (gtid & 1);
            wpb[gtid] = ((const float*)wih0)[ix];
        }
    }
    gbar_heavy(hcnt, hgen);
    // ---------------- P1 ----------------
    {
        int bb = gtid >> 9, nn = gtid & 511;
        float a = cpar[3072 + nn];
        const float* zr = zf + bb * Ln;
        for (int k = 0; k < Ln; ++k) a += zr[k] * cw1f[k * Hn + nn];
        ybuf[gtid] = a;
    }
    for (int e = gtid; e < 256 * Hn; e += NALL) {
        int nn = e >> 9, kk = e & 511;
        float w = wo1f[kk * 256 + nn];
        u16 hv = f2bf(w);
        wo1Th[e] = hv;
        wo1Tl[e] = f2bf(w - bf2f(hv));
    }
    gbar_heavy(hcnt, hgen);
    ln_leaky_row(ybuf + g * Hn, cpar + 0, cpar + 512, condf + g * Hn, red);
    gbar_heavy(hcnt, hgen);
    {
        float a = cpar[2560 + tid];
        const float* crow = condf + g * Hn;
        for (int k = 0; k < Hn; ++k) a += crow[k] * cw2f[k * Hn + tid];
        ybuf[g * Hn + tid] = a;
    }
    gbar_heavy(hcnt, hgen);
    ln_leaky_row(ybuf + g * Hn, cpar + 1024, cpar + 1536, condf + g * Hn, red);
    gbar_heavy(hcnt, hgen);
    if (isbf) phase5<true>(wih0, emb, condf, bias0f, base0, embW, gtid);
    else phase5<false>(wih0, emb, condf, bias0f, base0, embW, gtid);
    gbar_heavy(hcnt, hgen);  // L2 invalidated: cached reads see fresh staged data

    // ---------------- main loop ----------------
    float c0 = 0.f, c1 = 0.f;
    const int lr = tid >> 4;          // local row 0..31
    const int un = tid & 15;          // unit within block
    const int bb = R0g + lr;
    const int uu = ut * 16 + un;
    const float* bo1f = cpar + 2048;
    const float* bo2f = cpar + 2304;
    const float* wo2f = cpar + 3584;
    const int srow = tid >> 4;        // staging row 0..31
    const int kub = (tid & 15) * 32;  // staging u32 offset
    const bool headwg = (ut < 16);
    f32x4 acc1c[2] = {Z4, Z4};

    for (int e = tid; e < RPG * LSTR; e += NTHR) {
        lh0h[e] = 0; lh0l[e] = 0; lh1h[e] = 0; lh1l[e] = 0;
    }
    if (tid < 64) pvs[tid] = isbf ? bf2f(((const u16*)init_t)[tid & 1])
                                  : ((const float*)init_t)[tid & 1];

    for (int t = 0; t < Tn; ++t) {
        // ==== A: stage h1(t-1); head1+partials (ut<16, wave0); main GEMMs; gates0 ====
        if (t >= 1) {
            poll32(gf, 2 * (u32)t);
            u32 w[16];
            const u32* src = h1p + (size_t)(R0g + srow) * Hn + kub;
            cload16(src, w);
            unpack16(w, lh1h + srow * LSTR + kub, lh1l + srow * LSTR + kub);
            cload16(src + 16, w);
            unpack16(w, lh1h + srow * LSTR + kub + 16, lh1l + srow * LSTR + kub + 16);
        }
        __syncthreads();
        if (headwg && wv == 0 && t >= 1) {
            f32x4 ha[2][3] = {{Z4, Z4, Z4}, {Z4, Z4, Z4}};
            gemm32_3(lh1h, lh1l, wo1Th, wo1Tl, ut * 16, n, q, ha);
            float p[2][4][2];
#pragma unroll
            for (int Mh = 0; Mh < 2; ++Mh)
#pragma unroll
                for (int r = 0; r < 4; ++r) {
                    float hv = leaky(ha[Mh][0][r] + ha[Mh][1][r] + ha[Mh][2][r] +
                                     bo1f[ut * 16 + n]);
                    p[Mh][r][0] = hv * wo2f[(ut * 16 + n) * 2];
                    p[Mh][r][1] = hv * wo2f[(ut * 16 + n) * 2 + 1];
                }
#pragma unroll
            for (int Mh = 0; Mh < 2; ++Mh)
#pragma unroll
                for (int r = 0; r < 4; ++r)
#pragma unroll
                    for (int j = 0; j < 2; ++j) {
                        float s = p[Mh][r][j];
                        s += __shfl_xor(s, 1, 16);
                        s += __shfl_xor(s, 2, 16);
                        s += __shfl_xor(s, 4, 16);
                        s += __shfl_xor(s, 8, 16);
                        p[Mh][r][j] = s;
                    }
            if (n == 0) {
#pragma unroll
                for (int Mh = 0; Mh < 2; ++Mh)
#pragma unroll
                    for (int r = 0; r < 4; ++r)
#pragma unroll
                        for (int j = 0; j < 2; ++j) {
                            int row = Mh * 16 + q * 4 + r;
                            cstore1((u32*)(part + (row * 2 + j) * 16 + ut),
                                    f2u(p[Mh][r][j]));
                        }
            }
            cwait();
            if (tid == 0) cstore1(gf2 + ut, (u32)t);
        }
        {
            f32x4 aA[2][3] = {{Z4, Z4, Z4}, {Z4, Z4, Z4}};
            if (mat == 0) {
                gemm32_3(lh0h, lh0l, W0hi, W0lo, colb, n, q, aA);
#pragma unroll
                for (int Mh = 0; Mh < 2; ++Mh)
#pragma unroll
                    for (int r = 0; r < 4; ++r)
                        smemx[gw * 512 + (Mh * 16 + q * 4 + r) * 16 + n] =
                            aA[Mh][0][r] + aA[Mh][1][r] + aA[Mh][2][r];
            } else {
                gemm32_3(lh1h, lh1l, W1hi, W1lo, colb, n, q, aA);
                acc1c[0] = aA[0][0] + aA[0][1] + aA[0][2];
                acc1c[1] = aA[1][0] + aA[1][1] + aA[1][2];
            }
        }
        if (t >= 1) {
            poll16(gf2, (u32)t);
            if (tid < 64) {
                int row = tid >> 1, j = tid & 1;
                u32 hw[16];
                cload16((const u32*)(part + (row * 2 + j) * 16), hw);
                float s = bo2f[j];
#pragma unroll
                for (int i = 0; i < 16; ++i) s += u2f(hw[i]);
                float y = softplus(s) + 0.005f;
                pvs[row * 2 + j] = y;
                if (ut == 0) {
                    size_t oi = ((size_t)(R0g + row) * Tn + (t - 1)) * 2 + j;
                    if (isbf) ((u16*)outp)[oi] = f2bf(y);
                    else ((float*)outp)[oi] = y;
                }
            }
        }
        __syncthreads();
        {
            int id = char_ids[bb * Tn + t];
            float pv0 = pvs[lr * 2], pv1 = pvs[lr * 2 + 1];
            float gv[4];
#pragma unroll
            for (int gi = 0; gi < 4; ++gi) {
                int cc = gi * 512 + uu;
                gv[gi] = smemx[gi * 512 + lr * 16 + un] + base0[(size_t)bb * G4 + cc] +
                         embW[(size_t)id * G4 + cc] + pv0 * wpb[2 * cc] + pv1 * wpb[2 * cc + 1];
            }
            float ig = sigm(gv[0]), fg = sigm(gv[1]), gg = tanhf(gv[2]), og = sigm(gv[3]);
            c0 = fg * c0 + ig * gg;
            float h = og * tanhf(c0);
            u16 hv = f2bf(h);
            u16 lv = f2bf(h - bf2f(hv));
            cstore1(h0p + (size_t)bb * Hn + uu, (u32)hv | ((u32)lv << 16));
        }
        cwait();
        __syncthreads();
        if (tid == 0) cstore1(gfl, 2 * (u32)t + 1);

        // ==== B: stage h0(t); wih1 GEMM (mat1 waves); gates1 ====
        poll32(gf, 2 * (u32)t + 1);
        {
            u32 w[16];
            const u32* src = h0p + (size_t)(R0g + srow) * Hn + kub;
            cload16(src, w);
            unpack16(w, lh0h + srow * LSTR + kub, lh0l + srow * LSTR + kub);
            cload16(src + 16, w);
            unpack16(w, lh0h + srow * LSTR + kub + 16, lh0l + srow * LSTR + kub + 16);
        }
        __syncthreads();
        if (mat == 1) {
            f32x4 aB[2][3] = {{Z4, Z4, Z4}, {Z4, Z4, Z4}};
            gemm32_3(lh0h, lh0l, Wi1hi, Wi1lo, colb, n, q, aB);
            acc1c[0] = acc1c[0] + aB[0][0] + aB[0][1] + aB[0][2];
            acc1c[1] = acc1c[1] + aB[1][0] + aB[1][1] + aB[1][2];
#pragma unroll
            for (int Mh = 0; Mh < 2; ++Mh)
#pragma unroll
                for (int r = 0; r < 4; ++r)
                    smemx[gw * 512 + (Mh * 16 + q * 4 + r) * 16 + n] = acc1c[Mh][r];
        }
        __syncthreads();
        {
            float gv[4];
#pragma unroll
            for (int gi = 0; gi < 4; ++gi) {
                int cc = gi * 512 + uu;
                gv[gi] = smemx[gi * 512 + lr * 16 + un] + b1sum[cc];
            }
            float ig = sigm(gv[0]), fg = sigm(gv[1]), gg = tanhf(gv[2]), og = sigm(gv[3]);
            c1 = fg * c1 + ig * gg;
            float h = og * tanhf(c1);
            u16 hv = f2bf(h);
            u16 lv = f2bf(h - bf2f(hv));
            cstore1(h1p + (size_t)bb * Hn + uu, (u32)hv | ((u32)lv << 16));
        }
        cwait();
        __syncthreads();
        if (tid == 0) cstore1(gfl, 2 * (u32)t + 2);
    }

    // ---------------- epilogue: head for t = 511 ----------------
    poll32(gf, 2 * (u32)Tn);
    {
        u32 w[16];
        const u32* src = h1p + (size_t)(R0g + srow) * Hn + kub;
        cload16(src, w);
        unpack16(w, lh1h + srow * LSTR + kub, lh1l + srow * LSTR + kub);
        cload16(src + 16, w);
        unpack16(w, lh1h + srow * LSTR + kub + 16, lh1l + srow * LSTR + kub + 16);
    }
    __syncthreads();
    if (headwg && wv == 0) {
        f32x4 ha[2][3] = {{Z4, Z4, Z4}, {Z4, Z4, Z4}};
        gemm32_3(lh1h, lh1l, wo1Th, wo1Tl, ut * 16, n, q, ha);
        float p[2][4][2];
#pragma unroll
        for (int Mh = 0; Mh < 2; ++Mh)
#pragma unroll
            for (int r = 0; r < 4; ++r) {
                float hv = leaky(ha[Mh][0][r] + ha[Mh][1][r] + ha[Mh][2][r] + bo1f[ut * 16 + n]);
                p[Mh][r][0] = hv * wo2f[(ut * 16 + n) * 2];
                p[Mh][r][1] = hv * wo2f[(ut * 16 + n) * 2 + 1];
            }
#pragma unroll
        for (int Mh = 0; Mh < 2; ++Mh)
#pragma unroll
            for (int r = 0; r < 4; ++r)
#pragma unroll
                for (int j = 0; j < 2; ++j) {
                    float s = p[Mh][r][j];
                    s += __shfl_xor(s, 1, 16);
                    s += __shfl_xor(s, 2, 16);
                    s += __shfl_xor(s, 4, 16);
                    s += __shfl_xor(s, 8, 16);
                    p[Mh][r][j] = s;
                }
        if (n == 0) {
#pragma unroll
            for (int Mh = 0; Mh < 2; ++Mh)
#pragma unroll
                for (int r = 0; r < 4; ++r)
#pragma unroll
                    for (int j = 0; j < 2; ++j) {
                        int row = Mh * 16 + q * 4 + r;
                        cstore1((u32*)(part + (row * 2 + j) * 16 + ut), f2u(p[Mh][r][j]));
                    }
        }
        cwait();
        if (tid == 0) cstore1(gf2 + ut, (u32)Tn);
    }
    poll16(gf2, (u32)Tn);
    if (ut == 0 && tid < 64) {
        int row = tid >> 1, j = tid & 1;
        u32 hw[16];
        cload16((const u32*)(part + (row * 2 + j) * 16), hw);
        float s = bo2f[j];
#pragma unroll
        for (int i = 0; i < 16; ++i) s += u2f(hw[i]);
        float y = softplus(s) + 0.005f;
        size_t oi = ((size_t)(R0g + row) * Tn + (Tn - 1)) * 2 + j;
        if (isbf) ((u16*)outp)[oi] = f2bf(y);
        else ((float*)outp)[oi] = y;
    }
}

extern "C" void kernel_launch(void* const* d_in, const int* in_sizes, int n_in,
                              void* d_out, int out_size, void* d_ws, size_t ws_size,
                              hipStream_t stream) {
    (void)in_sizes; (void)n_in; (void)out_size; (void)ws_size;
    init_flags_kernel<<<1, 1024, 0, stream>>>((int*)d_ws);
    gen_kernel<<<WGS, NTHR, 0, stream>>>(
        (const int*)d_in[0], d_in[1], d_in[2], d_in[3], d_in[4], d_in[5], d_in[6], d_in[7],
        d_in[8], d_in[9], d_in[10], d_in[11], d_in[12], d_in[13], d_in[14], d_in[15], d_in[16],
        d_in[17], d_in[18], d_in[19], d_in[20], d_in[21], d_in[22], d_in[23],
        d_out, (char*)d_ws);
}

// Round 9
// 12622.044 us; speedup vs baseline: 1.9498x; 1.1823x over previous
//
#include <hip/hip_runtime.h>

// Problem constants
#define Bn 128
#define Tn 512
#define Vn 128
#define En 64
#define Ln 128
#define Hn 512
#define G4 2048
#define WGS 256
#define NTHR 512
#define NALL (WGS * NTHR)
#define LSTR 520   // LDS row stride in u16 (16B-aligned rows)
#define GRPS 8
#define WPG 32     // WGs per group
#define RPG 16     // batch rows per group

typedef unsigned short u16;
typedef unsigned int u32;
typedef __bf16 bf16x8 __attribute__((ext_vector_type(8)));
typedef float f32x4 __attribute__((ext_vector_type(4)));
typedef u32 u32x4 __attribute__((ext_vector_type(4)));

__device__ inline float bf2f(u16 h) {
    u32 u = ((u32)h) << 16;
    float f;
    __builtin_memcpy(&f, &u, 4);
    return f;
}
__device__ inline u16 f2bf(float f) {
    u32 u;
    __builtin_memcpy(&u, &f, 4);
    u32 r = (u + 0x7fffu + ((u >> 16) & 1u)) >> 16;
    return (u16)r;
}
__device__ inline u32 f2u(float f) { u32 u; __builtin_memcpy(&u, &f, 4); return u; }
__device__ inline float u2f(u32 u) { float f; __builtin_memcpy(&f, &u, 4); return f; }
__device__ inline float sigm(float x) { return 1.f / (1.f + expf(-x)); }
__device__ inline float leaky(float x) { return x > 0.f ? x : 0.2f * x; }
__device__ inline float softplus(float x) {
    return x > 0.f ? x + log1pf(expf(-x)) : log1pf(expf(x));
}

// ---- coherent (device-scope) vector ops; waitcnt INSIDE asm (round-5 lesson) ----
__device__ inline void cload16(const u32* p, u32* w) {
    u32x4 v0, v1, v2, v3;
    asm volatile(
        "global_load_dwordx4 %0, %4, off sc0 sc1\n\t"
        "global_load_dwordx4 %1, %4, off offset:16 sc0 sc1\n\t"
        "global_load_dwordx4 %2, %4, off offset:32 sc0 sc1\n\t"
        "global_load_dwordx4 %3, %4, off offset:48 sc0 sc1\n\t"
        "s_waitcnt vmcnt(0)"
        : "=&v"(v0), "=&v"(v1), "=&v"(v2), "=&v"(v3)
        : "v"(p)
        : "memory");
    *(u32x4*)(w) = v0;
    *(u32x4*)(w + 4) = v1;
    *(u32x4*)(w + 8) = v2;
    *(u32x4*)(w + 12) = v3;
}
__device__ inline u32 cload1(const u32* p) {
    u32 v;
    asm volatile("global_load_dword %0, %1, off sc0 sc1\n\ts_waitcnt vmcnt(0)"
                 : "=v"(v) : "v"(p) : "memory");
    return v;
}
__device__ inline void cwait() { asm volatile("s_waitcnt vmcnt(0)" ::: "memory"); }
__device__ inline void cstore1(u32* p, u32 v) {
    asm volatile("global_store_dword %0, %1, off sc0 sc1" :: "v"(p), "v"(v) : "memory");
}

// Workspace layout (bytes)
#define OFF_FLAGS  0x000000   // grp: 32 step slots @ grp*64, 16 head slots @ grp*64+32; heavy cnt@512 gen@528
#define OFF_B1SUM  0x002000
#define OFF_WP     0x004000
#define OFF_BIAS0  0x008000
#define OFF_CPAR   0x00A000   // f32: cg1,cbeta1,cg2,cbeta2; bo1@2048, bo2@2304, cb2@2560, cb1@3072, wo2f@3584
#define OFF_H0P    0x010000   // 128x512 u32 (hi|lo<<16)
#define OFF_H1P    0x050000
#define OFF_PART   0x090000   // partials: grp*1024 f32: [row][j][16]
#define OFF_WO1TH  0x0B0000   // 256x512 bf16
#define OFF_WO1TL  0x0F0000
#define OFF_ZF     0x130000
#define OFF_CW1F   0x140000
#define OFF_CW2F   0x180000
#define OFF_CONDF  0x280000
#define OFF_YBUF   0x2C0000
#define OFF_BASE0  0x300000   // 1MB f32 (temp: wo1f in P0/P1)
#define OFF_EMBW   0x400000
#define OFF_W0HI   0x500000   // 2048x512 bf16 each
#define OFF_W0LO   0x700000
#define OFF_W1HI   0x900000
#define OFF_W1LO   0xB00000
#define OFF_WI1HI  0xD00000
#define OFF_WI1LO  0xF00000   // end 0x1100000

// heavy grid barrier (pre-phase only)
__device__ inline void gbar_heavy(int* cnt, int* gen) {
    __syncthreads();
    if (threadIdx.x == 0) {
        __threadfence();
        int g = __hip_atomic_load(gen, __ATOMIC_RELAXED, __HIP_MEMORY_SCOPE_AGENT);
        int arrived = __hip_atomic_fetch_add(cnt, 1, __ATOMIC_ACQ_REL, __HIP_MEMORY_SCOPE_AGENT);
        if (arrived == WGS - 1) {
            __hip_atomic_store(cnt, 0, __ATOMIC_RELAXED, __HIP_MEMORY_SCOPE_AGENT);
            __hip_atomic_store(gen, g + 1, __ATOMIC_RELEASE, __HIP_MEMORY_SCOPE_AGENT);
        } else {
            while (__hip_atomic_load(gen, __ATOMIC_ACQUIRE, __HIP_MEMORY_SCOPE_AGENT) == g)
                __builtin_amdgcn_s_sleep(1);
        }
        __threadfence();
    }
    __syncthreads();
}

// polls (called by wave 0 only; broadcast via the following __syncthreads)
__device__ inline void poll32(const u32* gf, u32 sq) {
    const int l = threadIdx.x & 31;
    for (;;) {
        u32 v = cload1(gf + l);
        if (__all((int)(v >= sq))) break;
        __builtin_amdgcn_s_sleep(4);
    }
}
__device__ inline void poll16(const u32* gf, u32 sq) {
    const int l = threadIdx.x & 15;
    for (;;) {
        u32 v = cload1(gf + l);
        if (__all((int)(v >= sq))) break;
        __builtin_amdgcn_s_sleep(4);
    }
}

// unpack 16 packed u32 (hi|lo<<16) into bf16 hi/lo planes
__device__ inline void unpack16(const u32* w, u16* ph, u16* pl) {
    u32 hd[8], ld[8];
#pragma unroll
    for (int i = 0; i < 8; ++i) {
        hd[i] = (w[2 * i] & 0xFFFFu) | (w[2 * i + 1] << 16);
        ld[i] = (w[2 * i] >> 16) | (w[2 * i + 1] & 0xFFFF0000u);
    }
    *(u32x4*)(ph) = *(const u32x4*)(hd);
    *(u32x4*)(ph + 8) = *(const u32x4*)(hd + 4);
    *(u32x4*)(pl) = *(const u32x4*)(ld);
    *(u32x4*)(pl + 8) = *(const u32x4*)(ld + 4);
}

// M=16/N=16 tile, 3 hi/lo chains, K=512
#define MF(a, b, c) __builtin_amdgcn_mfma_f32_16x16x32_bf16(a, b, c, 0, 0, 0)
__device__ inline f32x4 gemm16_3(const u16* __restrict__ Ah, const u16* __restrict__ Al,
                                 const u16* __restrict__ Bhb, const u16* __restrict__ Blb,
                                 int colb, int n, int q) {
    const u16* Bh = Bhb + (size_t)(colb + n) * Hn;
    const u16* Bl = Blb + (size_t)(colb + n) * Hn;
    const int a0 = n * LSTR;
    f32x4 c0 = {0.f, 0.f, 0.f, 0.f}, c1 = c0, c2 = c0;
#pragma unroll 4
    for (int it = 0; it < 16; ++it) {
        const int ko = it * 32 + q * 8;
        bf16x8 bh = *(const bf16x8*)(Bh + ko);
        bf16x8 bl = *(const bf16x8*)(Bl + ko);
        bf16x8 ah = *(const bf16x8*)(Ah + a0 + ko);
        bf16x8 al = *(const bf16x8*)(Al + a0 + ko);
        c0 = MF(ah, bh, c0);
        c1 = MF(al, bh, c1);
        c2 = MF(ah, bl, c2);
    }
    return c0 + c1 + c2;
}

// dtype-safe staging (pre-phase)
__device__ inline void stage(float* dst, const void* src, int n, int gtid, bool isbf) {
    if (isbf) {
        const u16* s = (const u16*)src;
        for (int e = gtid; e < n; e += NALL) dst[e] = bf2f(s[e]);
    } else {
        const float* s = (const float*)src;
        for (int e = gtid; e < n; e += NALL) dst[e] = s[e];
    }
}
__device__ inline void stage_split(u16* hi, u16* lo, const void* src, int n, int gtid, bool isbf) {
    if (isbf) {
        const u16* s = (const u16*)src;
        for (int e = gtid; e < n; e += NALL) { hi[e] = s[e]; lo[e] = 0; }
    } else {
        const float* s = (const float*)src;
        for (int e = gtid; e < n; e += NALL) {
            float w = s[e];
            u16 h = f2bf(w);
            hi[e] = h;
            lo[e] = f2bf(w - bf2f(h));
        }
    }
}

template <bool ISBF>
__device__ inline float ldw(const void* p, size_t i) {
    if constexpr (ISBF) return bf2f(((const u16*)p)[i]);
    else return ((const float*)p)[i];
}

template <bool ISBF>
__device__ void phase5(const void* wih0, const void* emb, const float* __restrict__ condf,
                       const float* __restrict__ bias0f, float* __restrict__ base0,
                       float* __restrict__ embW, int gtid) {
    const int cc = gtid & 2047;
    const int bb0 = gtid >> 11;
    float b = bias0f[cc];
    float a0 = b, a1 = b, a2 = b, a3 = b;
    const float* c0p = condf + (size_t)bb0 * Hn;
    const float* c1p = condf + (size_t)(bb0 + 32) * Hn;
    const float* c2p = condf + (size_t)(bb0 + 64) * Hn;
    const float* c3p = condf + (size_t)(bb0 + 96) * Hn;
    const size_t wb = (size_t)cc * 578 + 64;
    for (int k = 0; k < Hn; ++k) {
        float w = ldw<ISBF>(wih0, wb + k);
        a0 += c0p[k] * w; a1 += c1p[k] * w; a2 += c2p[k] * w; a3 += c3p[k] * w;
    }
    base0[(size_t)bb0 * G4 + cc] = a0;
    base0[(size_t)(bb0 + 32) * G4 + cc] = a1;
    base0[(size_t)(bb0 + 64) * G4 + cc] = a2;
    base0[(size_t)(bb0 + 96) * G4 + cc] = a3;
    float e0 = 0.f, e1 = 0.f, e2 = 0.f, e3 = 0.f;
    const size_t wb2 = (size_t)cc * 578;
    for (int k = 0; k < En; ++k) {
        float w = ldw<ISBF>(wih0, wb2 + k);
        e0 += ldw<ISBF>(emb, (size_t)bb0 * En + k) * w;
        e1 += ldw<ISBF>(emb, (size_t)(bb0 + 32) * En + k) * w;
        e2 += ldw<ISBF>(emb, (size_t)(bb0 + 64) * En + k) * w;
        e3 += ldw<ISBF>(emb, (size_t)(bb0 + 96) * En + k) * w;
    }
    embW[(size_t)bb0 * G4 + cc] = e0;
    embW[(size_t)(bb0 + 32) * G4 + cc] = e1;
    embW[(size_t)(bb0 + 64) * G4 + cc] = e2;
    embW[(size_t)(bb0 + 96) * G4 + cc] = e3;
}

__device__ inline void ln_leaky_row(const float* __restrict__ x, const float* __restrict__ gamma,
                                    const float* __restrict__ beta, float* __restrict__ out,
                                    float* red) {
    int tid = threadIdx.x;
    float v = x[tid];
    float s = v, s2 = v * v;
    for (int off = 32; off; off >>= 1) {
        s += __shfl_down(s, off);
        s2 += __shfl_down(s2, off);
    }
    int wv = tid >> 6;
    if ((tid & 63) == 0) { red[wv * 2] = s; red[wv * 2 + 1] = s2; }
    __syncthreads();
    if (tid == 0) {
        float ts = 0.f, ts2 = 0.f;
        for (int i = 0; i < 8; ++i) { ts += red[i * 2]; ts2 += red[i * 2 + 1]; }
        float m = ts / 512.f;
        float var = ts2 / 512.f - m * m;
        red[16] = m;
        red[17] = rsqrtf(var + 1e-5f);
    }
    __syncthreads();
    float m = red[16], rs = red[17];
    out[tid] = leaky((v - m) * rs * gamma[tid] + beta[tid]);
    __syncthreads();
}

__global__ void init_flags_kernel(int* flags) { flags[threadIdx.x] = 0; }

__global__ __launch_bounds__(NTHR, 4) void gen_kernel(
    const int* __restrict__ char_ids, const void* z, const void* emb,
    const void* cw1, const void* cb1, const void* cg1, const void* cbeta1,
    const void* cw2, const void* cb2, const void* cg2, const void* cbeta2,
    const void* wih0, const void* whh0, const void* bih0, const void* bhh0,
    const void* wih1, const void* whh1, const void* bih1, const void* bhh1,
    const void* wo1, const void* bo1, const void* wo2, const void* bo2,
    const void* init_t, void* outp, char* __restrict__ ws) {
    __shared__ u16 lh0h[RPG * LSTR];
    __shared__ u16 lh0l[RPG * LSTR];
    __shared__ u16 lh1h[RPG * LSTR];
    __shared__ u16 lh1l[RPG * LSTR];
    __shared__ float smemx[1024];
    __shared__ float pvs[32];
    __shared__ float red[34];

    int* flags = (int*)(ws + OFF_FLAGS);
    float* b1sum = (float*)(ws + OFF_B1SUM);
    float* wpb = (float*)(ws + OFF_WP);
    float* bias0f = (float*)(ws + OFF_BIAS0);
    float* cpar = (float*)(ws + OFF_CPAR);
    u32* h0p = (u32*)(ws + OFF_H0P);
    u32* h1p = (u32*)(ws + OFF_H1P);
    float* partf = (float*)(ws + OFF_PART);
    u16* wo1Th = (u16*)(ws + OFF_WO1TH);
    u16* wo1Tl = (u16*)(ws + OFF_WO1TL);
    float* zf = (float*)(ws + OFF_ZF);
    float* cw1f = (float*)(ws + OFF_CW1F);
    float* cw2f = (float*)(ws + OFF_CW2F);
    float* condf = (float*)(ws + OFF_CONDF);
    float* ybuf = (float*)(ws + OFF_YBUF);
    float* base0 = (float*)(ws + OFF_BASE0);
    float* embW = (float*)(ws + OFF_EMBW);
    u16* W0hi = (u16*)(ws + OFF_W0HI);
    u16* W0lo = (u16*)(ws + OFF_W0LO);
    u16* W1hi = (u16*)(ws + OFF_W1HI);
    u16* W1lo = (u16*)(ws + OFF_W1LO);
    u16* Wi1hi = (u16*)(ws + OFF_WI1HI);
    u16* Wi1lo = (u16*)(ws + OFF_WI1LO);
    float* wo1f = base0;  // temp until P5

    const bool isbf = (((const u32*)cg1)[0] == 0x3F803F80u);

    const int g = blockIdx.x;
    const int tid = threadIdx.x;
    const int wv = tid >> 6;
    const int grp = g >> 5;     // 0..7: 16 batch rows each
    const int ut = g & 31;      // unit block: 16 cols x 4 gates
    const int mat = wv >> 2;    // 0: whh0-side, 1: whh1/wih1-side
    const int gw = wv & 3;      // gate
    const int R0g = grp * RPG;
    const int colb = gw * 512 + ut * 16;
    const int lane = tid & 63;
    const int n = lane & 15;
    const int q = lane >> 4;
    const int gtid = g * NTHR + tid;
    const f32x4 Z4 = {0.f, 0.f, 0.f, 0.f};

    u32* gf = (u32*)flags + grp * 64;       // 32 step slots
    u32* gf2 = (u32*)flags + grp * 64 + 32; // 16 head slots
    u32* gfl = gf + ut;
    int* hcnt = flags + 512;
    int* hgen = flags + 528;
    float* part = partf + grp * 1024;       // [row][j][16]

    // ---------------- P0: stage everything ----------------
    stage_split(W0hi, W0lo, whh0, G4 * Hn, gtid, isbf);
    stage_split(W1hi, W1lo, whh1, G4 * Hn, gtid, isbf);
    stage_split(Wi1hi, Wi1lo, wih1, G4 * Hn, gtid, isbf);
    stage(zf, z, Bn * Ln, gtid, isbf);
    stage(cw1f, cw1, Ln * Hn, gtid, isbf);
    stage(cw2f, cw2, Hn * Hn, gtid, isbf);
    stage(cpar + 0, cg1, 512, gtid, isbf);
    stage(cpar + 512, cbeta1, 512, gtid, isbf);
    stage(cpar + 1024, cg2, 512, gtid, isbf);
    stage(cpar + 1536, cbeta2, 512, gtid, isbf);
    stage(cpar + 2048, bo1, 256, gtid, isbf);
    stage(cpar + 2304, bo2, 2, gtid, isbf);
    stage(cpar + 2560, cb2, 512, gtid, isbf);
    stage(cpar + 3072, cb1, 512, gtid, isbf);
    stage(cpar + 3584, wo2, 256 * 2, gtid, isbf);
    stage(wo1f, wo1, Hn * 256, gtid, isbf);
    if (gtid < Bn * Hn) { cstore1(h0p + gtid, 0); cstore1(h1p + gtid, 0); }
    if (isbf) {
        if (gtid < G4) b1sum[gtid] = bf2f(((const u16*)bih1)[gtid]) + bf2f(((const u16*)bhh1)[gtid]);
        if (gtid < G4) bias0f[gtid] = bf2f(((const u16*)bih0)[gtid]) + bf2f(((const u16*)bhh0)[gtid]);
        if (gtid < 4096) {
            size_t ix = (size_t)(gtid >> 1) * 578 + 576 + (gtid & 1);
            wpb[gtid] = bf2f(((const u16*)wih0)[ix]);
        }
    } else {
        if (gtid < G4) b1sum[gtid] = ((const float*)bih1)[gtid] + ((const float*)bhh1)[gtid];
        if (gtid < G4) bias0f[gtid] = ((const float*)bih0)[gtid] + ((const float*)bhh0)[gtid];
        if (gtid < 4096) {
            size_t ix = (size_t)(gtid >> 1) * 578 + 576 + (gtid & 1);
            wpb[gtid] = ((const float*)wih0)[ix];
        }
    }
    gbar_heavy(hcnt, hgen);
    // ---------------- P1 ----------------
    if (gtid < Bn * Hn) {
        int bb = gtid >> 9, nn = gtid & 511;
        float a = cpar[3072 + nn];
        const float* zr = zf + bb * Ln;
        for (int k = 0; k < Ln; ++k) a += zr[k] * cw1f[k * Hn + nn];
        ybuf[gtid] = a;
    }
    for (int e = gtid; e < 256 * Hn; e += NALL) {
        int nn = e >> 9, kk = e & 511;
        float w = wo1f[kk * 256 + nn];
        u16 hv = f2bf(w);
        wo1Th[e] = hv;
        wo1Tl[e] = f2bf(w - bf2f(hv));
    }
    gbar_heavy(hcnt, hgen);
    if (g < Bn) ln_leaky_row(ybuf + g * Hn, cpar + 0, cpar + 512, condf + g * Hn, red);
    gbar_heavy(hcnt, hgen);
    if (g < Bn) {
        float a = cpar[2560 + tid];
        const float* crow = condf + g * Hn;
        for (int k = 0; k < Hn; ++k) a += crow[k] * cw2f[k * Hn + tid];
        ybuf[g * Hn + tid] = a;
    }
    gbar_heavy(hcnt, hgen);
    if (g < Bn) ln_leaky_row(ybuf + g * Hn, cpar + 1024, cpar + 1536, condf + g * Hn, red);
    gbar_heavy(hcnt, hgen);
    if (gtid < Bn * Hn) {
        if (isbf) phase5<true>(wih0, emb, condf, bias0f, base0, embW, gtid);
        else phase5<false>(wih0, emb, condf, bias0f, base0, embW, gtid);
    }
    gbar_heavy(hcnt, hgen);  // L2 invalidated: cached reads see fresh staged data

    // ---------------- main loop ----------------
    float c0 = 0.f, c1 = 0.f;
    const int lr = tid >> 4;          // local row 0..15 (for tid<256)
    const int un = tid & 15;
    const int bb = R0g + lr;
    const int uu = ut * 16 + un;
    const float* bo1f = cpar + 2048;
    const float* bo2f = cpar + 2304;
    const float* wo2f = cpar + 3584;
    const int srow = tid >> 5;        // staging row 0..15
    const int kub = (tid & 31) * 16;  // staging u32 offset
    const bool headwg = (ut < 16);
    f32x4 acc1c = Z4;

    for (int e = tid; e < RPG * LSTR; e += NTHR) {
        lh0h[e] = 0; lh0l[e] = 0; lh1h[e] = 0; lh1l[e] = 0;
    }
    if (tid < 32) pvs[tid] = isbf ? bf2f(((const u16*)init_t)[tid & 1])
                                  : ((const float*)init_t)[tid & 1];

    for (int t = 0; t < Tn; ++t) {
        // ==== A: stage h1(t-1); head (ut<16 wave0); main GEMMs; gates0 -> h0(t) ====
        if (t >= 1) {
            if (wv == 0) poll32(gf, 2 * (u32)t);
            __syncthreads();
            u32 w[16];
            cload16(h1p + (size_t)(R0g + srow) * Hn + kub, w);
            unpack16(w, lh1h + srow * LSTR + kub, lh1l + srow * LSTR + kub);
        }
        __syncthreads();
        if (headwg && wv == 0 && t >= 1) {
            f32x4 ha = gemm16_3(lh1h, lh1l, wo1Th, wo1Tl, ut * 16, n, q);
            float p[4][2];
#pragma unroll
            for (int r = 0; r < 4; ++r) {
                float hv = leaky(ha[r] + bo1f[ut * 16 + n]);
                p[r][0] = hv * wo2f[(ut * 16 + n) * 2];
                p[r][1] = hv * wo2f[(ut * 16 + n) * 2 + 1];
            }
#pragma unroll
            for (int r = 0; r < 4; ++r)
#pragma unroll
                for (int j = 0; j < 2; ++j) {
                    float s = p[r][j];
                    s += __shfl_xor(s, 1, 16);
                    s += __shfl_xor(s, 2, 16);
                    s += __shfl_xor(s, 4, 16);
                    s += __shfl_xor(s, 8, 16);
                    p[r][j] = s;
                }
            if (n == 0) {
#pragma unroll
                for (int r = 0; r < 4; ++r)
#pragma unroll
                    for (int j = 0; j < 2; ++j) {
                        int row = q * 4 + r;
                        cstore1((u32*)(part + (row * 2 + j) * 16 + ut), f2u(p[r][j]));
                    }
            }
            cwait();
            if (tid == 0) cstore1(gf2 + ut, (u32)t);
        }
        if (mat == 0) {
            f32x4 a = gemm16_3(lh0h, lh0l, W0hi, W0lo, colb, n, q);
#pragma unroll
            for (int r = 0; r < 4; ++r)
                smemx[gw * 256 + (q * 4 + r) * 16 + n] = a[r];
        } else {
            acc1c = gemm16_3(lh1h, lh1l, W1hi, W1lo, colb, n, q);
        }
        if (t >= 1) {
            if (wv == 0) {
                poll16(gf2, (u32)t);
                if (tid < 32) {
                    int row = tid >> 1, j = tid & 1;
                    u32 hw[16];
                    cload16((const u32*)(part + (row * 2 + j) * 16), hw);
                    float s = bo2f[j];
#pragma unroll
                    for (int i = 0; i < 16; ++i) s += u2f(hw[i]);
                    float y = softplus(s) + 0.005f;
                    pvs[row * 2 + j] = y;
                    if (ut == 0) {
                        size_t oi = ((size_t)(R0g + row) * Tn + (t - 1)) * 2 + j;
                        if (isbf) ((u16*)outp)[oi] = f2bf(y);
                        else ((float*)outp)[oi] = y;
                    }
                }
            }
        }
        __syncthreads();
        if (tid < 256) {
            int id = char_ids[bb * Tn + t];
            float pv0 = pvs[lr * 2], pv1 = pvs[lr * 2 + 1];
            float gv[4];
#pragma unroll
            for (int gi = 0; gi < 4; ++gi) {
                int cc = gi * 512 + uu;
                gv[gi] = smemx[gi * 256 + lr * 16 + un] + base0[(size_t)bb * G4 + cc] +
                         embW[(size_t)id * G4 + cc] + pv0 * wpb[2 * cc] + pv1 * wpb[2 * cc + 1];
            }
            float ig = sigm(gv[0]), fg = sigm(gv[1]), gg = tanhf(gv[2]), og = sigm(gv[3]);
            c0 = fg * c0 + ig * gg;
            float h = og * tanhf(c0);
            u16 hv = f2bf(h);
            u16 lv = f2bf(h - bf2f(hv));
            cstore1(h0p + (size_t)bb * Hn + uu, (u32)hv | ((u32)lv << 16));
        }
        cwait();
        __syncthreads();
        if (tid == 0) cstore1(gfl, 2 * (u32)t + 1);

        // ==== B: stage h0(t); wih1 GEMM (mat1 waves); gates1 -> h1(t) ====
        if (wv == 0) poll32(gf, 2 * (u32)t + 1);
        __syncthreads();
        {
            u32 w[16];
            cload16(h0p + (size_t)(R0g + srow) * Hn + kub, w);
            unpack16(w, lh0h + srow * LSTR + kub, lh0l + srow * LSTR + kub);
        }
        __syncthreads();
        if (mat == 1) {
            f32x4 a = gemm16_3(lh0h, lh0l, Wi1hi, Wi1lo, colb, n, q);
            acc1c = acc1c + a;
#pragma unroll
            for (int r = 0; r < 4; ++r)
                smemx[gw * 256 + (q * 4 + r) * 16 + n] = acc1c[r];
        }
        __syncthreads();
        if (tid < 256) {
            float gv[4];
#pragma unroll
            for (int gi = 0; gi < 4; ++gi) {
                int cc = gi * 512 + uu;
                gv[gi] = smemx[gi * 256 + lr * 16 + un] + b1sum[cc];
            }
            float ig = sigm(gv[0]), fg = sigm(gv[1]), gg = tanhf(gv[2]), og = sigm(gv[3]);
            c1 = fg * c1 + ig * gg;
            float h = og * tanhf(c1);
            u16 hv = f2bf(h);
            u16 lv = f2bf(h - bf2f(hv));
            cstore1(h1p + (size_t)bb * Hn + uu, (u32)hv | ((u32)lv << 16));
        }
        cwait();
        __syncthreads();
        if (tid == 0) cstore1(gfl, 2 * (u32)t + 2);
    }

    // ---------------- epilogue: head for t = 511 ----------------
    if (wv == 0) poll32(gf, 2 * (u32)Tn);
    __syncthreads();
    {
        u32 w[16];
        cload16(h1p + (size_t)(R0g + srow) * Hn + kub, w);
        unpack16(w, lh1h + srow * LSTR + kub, lh1l + srow * LSTR + kub);
    }
    __syncthreads();
    if (headwg && wv == 0) {
        f32x4 ha = gemm16_3(lh1h, lh1l, wo1Th, wo1Tl, ut * 16, n, q);
        float p[4][2];
#pragma unroll
        for (int r = 0; r < 4; ++r) {
            float hv = leaky(ha[r] + bo1f[ut * 16 + n]);
            p[r][0] = hv * wo2f[(ut * 16 + n) * 2];
            p[r][1] = hv * wo2f[(ut * 16 + n) * 2 + 1];
        }
#pragma unroll
        for (int r = 0; r < 4; ++r)
#pragma unroll
            for (int j = 0; j < 2; ++j) {
                float s = p[r][j];
                s += __shfl_xor(s, 1, 16);
                s += __shfl_xor(s, 2, 16);
                s += __shfl_xor(s, 4, 16);
                s += __shfl_xor(s, 8, 16);
                p[r][j] = s;
            }
        if (n == 0) {
#pragma unroll
            for (int r = 0; r < 4; ++r)
#pragma unroll
                for (int j = 0; j < 2; ++j) {
                    int row = q * 4 + r;
                    cstore1((u32*)(part + (row * 2 + j) * 16 + ut), f2u(p[r][j]));
                }
        }
        cwait();
        if (tid == 0) cstore1(gf2 + ut, (u32)Tn);
    }
    if (ut == 0 && wv == 0) {
        poll16(gf2, (u32)Tn);
        if (tid < 32) {
            int row = tid >> 1, j = tid & 1;
            u32 hw[16];
            cload16((const u32*)(part + (row * 2 + j) * 16), hw);
            float s = bo2f[j];
#pragma unroll
            for (int i = 0; i < 16; ++i) s += u2f(hw[i]);
            float y = softplus(s) + 0.005f;
            size_t oi = ((size_t)(R0g + row) * Tn + (Tn - 1)) * 2 + j;
            if (isbf) ((u16*)outp)[oi] = f2bf(y);
            else ((float*)outp)[oi] = y;
        }
    }
}

extern "C" void kernel_launch(void* const* d_in, const int* in_sizes, int n_in,
                              void* d_out, int out_size, void* d_ws, size_t ws_size,
                              hipStream_t stream) {
    (void)in_sizes; (void)n_in; (void)out_size; (void)ws_size;
    init_flags_kernel<<<1, 1024, 0, stream>>>((int*)d_ws);
    gen_kernel<<<WGS, NTHR, 0, stream>>>(
        (const int*)d_in[0], d_in[1], d_in[2], d_in[3], d_in[4], d_in[5], d_in[6], d_in[7],
        d_in[8], d_in[9], d_in[10], d_in[11], d_in[12], d_in[13], d_in[14], d_in[15], d_in[16],
        d_in[17], d_in[18], d_in[19], d_in[20], d_in[21], d_in[22], d_in[23],
        d_out, (char*)d_ws);
}